// Round 4
// baseline (3034.231 us; speedup 1.0000x reference)
//
#include <hip/hip_runtime.h>
#include <stdint.h>

#define NBN   25088   // 128 * 196  (TB * N)
#define NTOK  196
#define BATCH 32
#define CDIM  384
#define HDIM  1536
#define NHEAD 12

// ---------------- transpose: x (TB,C,N) -> xT (C, TB*N) ------------------------
__global__ __launch_bounds__(256) void k_transpose(const float* __restrict__ x,
                                                   float* __restrict__ xT) {
  int id = blockIdx.x * 256 + threadIdx.x;
  int c = id / NBN;
  int r = id - c * NBN;
  int b = r / NTOK;
  int n = r - b * NTOK;
  xT[id] = x[((size_t)b * CDIM + c) * NTOK + n];
}

// ---------------------------------------------------------------------------
// fp32 GEMM, chain-exact (k-ascending fmaf per output), BK=32, prefetched,
// fused f64 BN partial sums. B source: float (K,NBN) or packed spike bits.
// Packed layout: pk[ch][tb(=t*32+b)][8 x u32], bit = n (0..195), rest zero.
// ---------------------------------------------------------------------------
template <bool QKV, bool PACKED>
__global__ __launch_bounds__(256, 3) void k_gemm3(
    const float* __restrict__ W0, const float* __restrict__ W1,
    const float* __restrict__ W2, const float* __restrict__ Xf,
    const uint32_t* __restrict__ Xp, const float* __restrict__ bias,
    float* __restrict__ Y, double* __restrict__ pS, double* __restrict__ pS2,
    int K, int Mtot) {
  __shared__ float As[32][132];
  __shared__ float Bs[32][132];
  const int tid = threadIdx.x;
  const int bn = blockIdx.x, gy = blockIdx.y;
  const float* W;
  int wrow;
  if constexpr (QKV) {
    W = (gy < 3) ? W0 : (gy < 6) ? W1 : W2;
    wrow = (gy % 3) * 128;
  } else {
    W = W0;
    wrow = gy * 128;
  }
  const int orow = gy * 128;
  const int tx = tid & 15, ty = tid >> 4;
  const int NK = K >> 5;

  float acc[8][8];
#pragma unroll
  for (int i = 0; i < 8; ++i)
#pragma unroll
    for (int j = 0; j < 8; ++j) acc[i][j] = 0.f;

  float4 pa[4], pbf[4];
  uint32_t pmask = 0;

  // ---- prefetch tile 0 ----
#pragma unroll
  for (int i = 0; i < 4; ++i) {
    int id = tid + i * 256;
    int r = id >> 3, c4 = id & 7;
    pa[i] = *reinterpret_cast<const float4*>(&W[(size_t)(wrow + r) * K + c4 * 4]);
  }
  if constexpr (PACKED) {
    int r = tid >> 3, c16 = tid & 7;
    pmask = 0;
#pragma unroll
    for (int j = 0; j < 16; ++j) {
      unsigned c = bn * 128 + c16 * 16 + j;
      unsigned tb = c / 196u, nt = c % 196u;
      uint32_t w = Xp[((size_t)r * 128 + tb) * 8 + (nt >> 5)];
      pmask |= ((w >> (nt & 31)) & 1u) << j;
    }
  } else {
#pragma unroll
    for (int i = 0; i < 4; ++i) {
      int id = tid + i * 256;
      int r = id >> 5, c4 = id & 31;
      pbf[i] = *reinterpret_cast<const float4*>(&Xf[(size_t)r * NBN + bn * 128 + c4 * 4]);
    }
  }

  for (int ks = 0; ks < NK; ++ks) {
    __syncthreads();
    // ---- store prefetched tile to LDS ----
#pragma unroll
    for (int i = 0; i < 4; ++i) {
      int id = tid + i * 256;
      int r = id >> 3, c4 = id & 7;
      As[c4 * 4 + 0][r] = pa[i].x;
      As[c4 * 4 + 1][r] = pa[i].y;
      As[c4 * 4 + 2][r] = pa[i].z;
      As[c4 * 4 + 3][r] = pa[i].w;
    }
    if constexpr (PACKED) {
      int r = tid >> 3, c16 = tid & 7;
#pragma unroll
      for (int q = 0; q < 4; ++q) {
        float4 f;
        f.x = (pmask >> (q * 4 + 0)) & 1u ? 1.f : 0.f;
        f.y = (pmask >> (q * 4 + 1)) & 1u ? 1.f : 0.f;
        f.z = (pmask >> (q * 4 + 2)) & 1u ? 1.f : 0.f;
        f.w = (pmask >> (q * 4 + 3)) & 1u ? 1.f : 0.f;
        *reinterpret_cast<float4*>(&Bs[r][c16 * 16 + q * 4]) = f;
      }
    } else {
#pragma unroll
      for (int i = 0; i < 4; ++i) {
        int id = tid + i * 256;
        int r = id >> 5, c4 = id & 31;
        *reinterpret_cast<float4*>(&Bs[r][c4 * 4]) = pbf[i];
      }
    }
    __syncthreads();
    // ---- prefetch next tile (latency hidden under compute) ----
    if (ks + 1 < NK) {
      const int k0 = (ks + 1) << 5;
#pragma unroll
      for (int i = 0; i < 4; ++i) {
        int id = tid + i * 256;
        int r = id >> 3, c4 = id & 7;
        pa[i] = *reinterpret_cast<const float4*>(&W[(size_t)(wrow + r) * K + k0 + c4 * 4]);
      }
      if constexpr (PACKED) {
        int r = tid >> 3, c16 = tid & 7;
        uint32_t m2 = 0;
#pragma unroll
        for (int j = 0; j < 16; ++j) {
          unsigned c = bn * 128 + c16 * 16 + j;
          unsigned tb = c / 196u, nt = c % 196u;
          uint32_t w = Xp[((size_t)(k0 + r) * 128 + tb) * 8 + (nt >> 5)];
          m2 |= ((w >> (nt & 31)) & 1u) << j;
        }
        pmask = m2;
      } else {
#pragma unroll
        for (int i = 0; i < 4; ++i) {
          int id = tid + i * 256;
          int r = id >> 5, c4 = id & 31;
          pbf[i] = *reinterpret_cast<const float4*>(&Xf[(size_t)(k0 + r) * NBN + bn * 128 + c4 * 4]);
        }
      }
    }
    // ---- compute: k-ascending fused-FMA chain per output ----
#pragma unroll
    for (int kk = 0; kk < 32; ++kk) {
      float a8[8], b8[8];
      *reinterpret_cast<float4*>(&a8[0]) = *reinterpret_cast<const float4*>(&As[kk][ty * 8]);
      *reinterpret_cast<float4*>(&a8[4]) = *reinterpret_cast<const float4*>(&As[kk][ty * 8 + 4]);
      *reinterpret_cast<float4*>(&b8[0]) = *reinterpret_cast<const float4*>(&Bs[kk][tx * 8]);
      *reinterpret_cast<float4*>(&b8[4]) = *reinterpret_cast<const float4*>(&Bs[kk][tx * 8 + 4]);
#pragma unroll
      for (int i = 0; i < 8; ++i)
#pragma unroll
        for (int j = 0; j < 8; ++j) acc[i][j] = fmaf(a8[i], b8[j], acc[i][j]);
    }
  }

  // ---- epilogue: bias, store, f64 BN partials ----
#pragma unroll
  for (int i = 0; i < 8; ++i) {
    const int row = orow + ty * 8 + i;
    const float bv = bias ? bias[row] : 0.f;
    float4 o0, o1;
    o0.x = acc[i][0] + bv; o0.y = acc[i][1] + bv;
    o0.z = acc[i][2] + bv; o0.w = acc[i][3] + bv;
    o1.x = acc[i][4] + bv; o1.y = acc[i][5] + bv;
    o1.z = acc[i][6] + bv; o1.w = acc[i][7] + bv;
    *reinterpret_cast<float4*>(&Y[(size_t)row * NBN + bn * 128 + tx * 8]) = o0;
    *reinterpret_cast<float4*>(&Y[(size_t)row * NBN + bn * 128 + tx * 8 + 4]) = o1;
    double s = (double)o0.x + (double)o0.y + (double)o0.z + (double)o0.w +
               (double)o1.x + (double)o1.y + (double)o1.z + (double)o1.w;
    double s2 = (double)o0.x * o0.x + (double)o0.y * o0.y + (double)o0.z * o0.z +
                (double)o0.w * o0.w + (double)o1.x * o1.x + (double)o1.y * o1.y +
                (double)o1.z * o1.z + (double)o1.w * o1.w;
#pragma unroll
    for (int off = 1; off < 16; off <<= 1) {
      s += __shfl_xor(s, off, 64);
      s2 += __shfl_xor(s2, off, 64);
    }
    if (tx == 0) {
      pS[(size_t)bn * Mtot + row] = s;
      pS2[(size_t)bn * Mtot + row] = s2;
    }
  }
}

// ---- BN stat reduce: 196 f64 partials per channel --------------------------
__global__ __launch_bounds__(64) void k_bn_reduce3(const double* __restrict__ pS,
                                                   const double* __restrict__ pS2,
                                                   float* __restrict__ mean,
                                                   float* __restrict__ rstd, int Mtot) {
  const int ch = blockIdx.x, lane = threadIdx.x;
  double s = 0.0, s2 = 0.0;
  for (int j = lane; j < 196; j += 64) {
    s += pS[(size_t)j * Mtot + ch];
    s2 += pS2[(size_t)j * Mtot + ch];
  }
#pragma unroll
  for (int off = 32; off; off >>= 1) {
    s += __shfl_down(s, off, 64);
    s2 += __shfl_down(s2, off, 64);
  }
  if (lane == 0) {
    double m = s / (double)NBN;
    double v = s2 / (double)NBN - m * m;
    mean[ch] = (float)m;
    rstd[ch] = (float)(1.0 / sqrt(v + 1e-5));
  }
}

// ---- BN apply + LIF (thr 1.0) writing PACKED spikes ------------------------
// one block per channel; thread = (b = tid>>3, w = tid&7) covers 32 n-bits.
template <bool SEL3>
__global__ __launch_bounds__(256) void k_lif_pack(const float* __restrict__ Y,
    const float* __restrict__ mean, const float* __restrict__ rstd,
    const float* __restrict__ g0, const float* __restrict__ g1,
    const float* __restrict__ g2, const float* __restrict__ b0,
    const float* __restrict__ b1, const float* __restrict__ b2,
    uint32_t* __restrict__ pk) {
  const int o = blockIdx.x;
  const int b = threadIdx.x >> 3, w = threadIdx.x & 7;
  float g, be;
  if constexpr (SEL3) {
    int br = o / 384, ol = o - (o / 384) * 384;
    g = (br == 0 ? g0 : br == 1 ? g1 : g2)[ol];
    be = (br == 0 ? b0 : br == 1 ? b1 : b2)[ol];
  } else {
    g = g0[o];
    be = b0[o];
  }
  const float m_ = mean[o], rs_ = rstd[o];
  float mem[32];
#pragma unroll
  for (int j = 0; j < 32; ++j) mem[j] = 0.f;
  for (int t = 0; t < 4; ++t) {
    uint32_t word = 0;
    const size_t base = (size_t)o * NBN + (size_t)(t * 32 + b) * NTOK + w * 32;
#pragma unroll
    for (int q = 0; q < 8; ++q) {
      if (w * 32 + q * 4 < NTOK) {
        float4 v4 = *reinterpret_cast<const float4*>(&Y[base + q * 4]);
        float vv[4] = {v4.x, v4.y, v4.z, v4.w};
#pragma unroll
        for (int jj = 0; jj < 4; ++jj) {
          int j = q * 4 + jj;
          float v = ((vv[jj] - m_) * rs_) * g + be;
          float mm = mem[j];
          mm = mm + (v - mm) * 0.5f;
          bool fire = (mm >= 1.0f);
          mem[j] = fire ? 0.f : mm;
          word |= (fire ? 1u : 0u) << j;
        }
      }
    }
    pk[((size_t)o * 128 + t * 32 + b) * 8 + w] = word;
  }
}

// ---- BN apply + LIF (thr 1.0), float outputs -------------------------------
// MODE 1: xres(C,NBN) = xT + spike.  MODE 2: out(TB,C,N) = xres + spike.
template <int MODE>
__global__ __launch_bounds__(256) void k_bn_lif(const float* __restrict__ Y,
                                                const float* __restrict__ mean,
                                                const float* __restrict__ rstd,
                                                const float* __restrict__ gamma,
                                                const float* __restrict__ beta,
                                                const float* __restrict__ addsrc,
                                                float* __restrict__ extra) {
  int id = blockIdx.x * 256 + threadIdx.x;
  int o = id / (BATCH * NTOK);
  int r = id - o * (BATCH * NTOK);
  float m_ = mean[o], rs_ = rstd[o], g = gamma[o], be = beta[o];
  float mem = 0.f;
#pragma unroll
  for (int t = 0; t < 4; ++t) {
    size_t idx = (size_t)o * NBN + (size_t)t * (BATCH * NTOK) + r;
    float v = Y[idx];
    v = ((v - m_) * rs_) * g + be;
    mem = mem + (v - mem) * 0.5f;
    bool fire = (mem >= 1.0f);
    float s = fire ? 1.f : 0.f;
    mem = fire ? 0.f : mem;
    if constexpr (MODE == 1) {
      extra[idx] = addsrc[idx] + s;
    } else {
      int b = r / NTOK, n = r - b * NTOK;
      extra[((size_t)(t * BATCH + b) * CDIM + o) * NTOK + n] = addsrc[idx] + s;
    }
  }
}

// ---- attention via popcount (exact integers) -------------------------------
__global__ __launch_bounds__(256) void k_attn_pop(const uint32_t* __restrict__ pQ,
                                                  const uint32_t* __restrict__ pK,
                                                  const uint32_t* __restrict__ pV,
                                                  uint32_t* __restrict__ pA) {
  __shared__ __align__(16) uint32_t qw[32][8], kw[32][8], vw[32][8];
  __shared__ int kv[32][33];
  __shared__ uint32_t kvb[8][32];
  __shared__ uint32_t qT[NTOK];
  const int bh = blockIdx.x;
  const int b_ = bh / NHEAD, h = bh - b_ * NHEAD;
  const int tid = threadIdx.x;
  const int e = tid >> 3, w = tid & 7;
  float mem[32];
#pragma unroll
  for (int j = 0; j < 32; ++j) mem[j] = 0.f;

  for (int t = 0; t < 4; ++t) {
    const int tb = t * 32 + b_;
    {
      int d = tid >> 3, wo = tid & 7;
      size_t base = ((size_t)(h * 32 + d) * 128 + tb) * 8 + wo;
      qw[d][wo] = pQ[base];
      kw[d][wo] = pK[base];
      vw[d][wo] = pV[base];
    }
    __syncthreads();
    for (int i = tid; i < 1024; i += 256) {
      int d = i >> 5, ee = i & 31;
      const uint64_t* kp = reinterpret_cast<const uint64_t*>(&kw[d][0]);
      const uint64_t* vp = reinterpret_cast<const uint64_t*>(&vw[ee][0]);
      int s = 0;
#pragma unroll
      for (int u = 0; u < 4; ++u) s += __popcll(kp[u] & vp[u]);
      kv[d][ee] = s;
    }
    __syncthreads();
    {
      int bitb = tid >> 5, ee = tid & 31;
      uint32_t mword = 0;
#pragma unroll
      for (int d = 0; d < 32; ++d) mword |= (uint32_t)((kv[d][ee] >> bitb) & 1) << d;
      kvb[bitb][ee] = mword;
    }
    if (tid < NTOK) {
      uint32_t mword = 0;
#pragma unroll
      for (int d = 0; d < 32; ++d)
        mword |= ((qw[d][tid >> 5] >> (tid & 31)) & 1u) << d;
      qT[tid] = mword;
    }
    __syncthreads();
    uint32_t word = 0;
#pragma unroll
    for (int j = 0; j < 32; ++j) {
      int n = w * 32 + j;
      if (n < NTOK) {
        uint32_t qm = qT[n];
        int acc = 0;
#pragma unroll
        for (int bb = 0; bb < 8; ++bb) acc += __popc(qm & kvb[bb][e]) << bb;
        float val = (float)acc * 0.125f;
        float mm = mem[j];
        mm = mm + (val - mm) * 0.5f;
        bool fire = (mm >= 0.5f);
        mem[j] = fire ? 0.f : mm;
        word |= (fire ? 1u : 0u) << j;
      }
    }
    pA[((size_t)(h * 32 + e) * 128 + tb) * 8 + w] = word;
    __syncthreads();
  }
}

// ---------------------------------------------------------------------------
extern "C" void kernel_launch(void* const* d_in, const int* in_sizes, int n_in,
                              void* d_out, int out_size, void* d_ws, size_t ws_size,
                              hipStream_t stream) {
  const float* x          = (const float*)d_in[0];
  const float* q_w        = (const float*)d_in[1];
  const float* q_gamma    = (const float*)d_in[2];
  const float* q_beta     = (const float*)d_in[3];
  const float* k_w        = (const float*)d_in[4];
  const float* k_gamma    = (const float*)d_in[5];
  const float* k_beta     = (const float*)d_in[6];
  const float* v_w        = (const float*)d_in[7];
  const float* v_gamma    = (const float*)d_in[8];
  const float* v_beta     = (const float*)d_in[9];
  const float* proj_w     = (const float*)d_in[10];
  const float* proj_b     = (const float*)d_in[11];
  const float* proj_gamma = (const float*)d_in[12];
  const float* proj_beta  = (const float*)d_in[13];
  const float* fc1_w      = (const float*)d_in[14];
  const float* fc1_b      = (const float*)d_in[15];
  const float* bn1_gamma  = (const float*)d_in[16];
  const float* bn1_beta   = (const float*)d_in[17];
  const float* fc2_w      = (const float*)d_in[18];
  const float* fc2_b      = (const float*)d_in[19];
  const float* bn2_gamma  = (const float*)d_in[20];
  const float* bn2_beta   = (const float*)d_in[21];
  float* out = (float*)d_out;
  char* ws = (char*)d_ws;

  // ---- arena (bytes); peak ~210.1 MB < 231.2 MB proven in round 1 ----
  const size_t O_XT   = 0;           // xT f32 (384,NBN)       38,535,168
  const size_t O_YQ   = 38535168;    // yQKV f32 (1152,NBN)   115,605,504; also proj/fc2 yB
  const size_t O_XRES = 154140672;   // xres f32 (384,NBN)     38,535,168
  const size_t O_SPK  = 192675840;   // packed qkv spikes       4,718,592
  const size_t O_SPA  = 197394432;   // packed attn spikes      1,572,864
  const size_t O_H1PK = 198967296;   // packed h1 spikes        6,291,456
  const size_t O_PART = 205258752;   // f64 partials 2x 196*1536*8 = 4,816,896
  const size_t O_STAT = 210075648;   // mean/rstd f32 2x1536

  float* xT    = (float*)(ws + O_XT);
  float* yQ    = (float*)(ws + O_YQ);
  float* yB    = (float*)(ws + O_YQ);
  float* h1    = (float*)(ws + O_XT);   // spans [0, 154.1MB)
  float* xres  = (float*)(ws + O_XRES);
  uint32_t* pkQKV = (uint32_t*)(ws + O_SPK);
  uint32_t* pkA   = (uint32_t*)(ws + O_SPA);
  uint32_t* pkH1  = (uint32_t*)(ws + O_H1PK);
  double* pS   = (double*)(ws + O_PART);
  double* pS2  = (double*)(ws + O_PART + 2408448);
  float* mean  = (float*)(ws + O_STAT);
  float* rstd  = (float*)(ws + O_STAT + 6144);

  // 1. transpose
  k_transpose<<<dim3(CDIM * NBN / 256), 256, 0, stream>>>(x, xT);

  // 2. fused q/k/v GEMM (chain-exact) + fused BN partials
  k_gemm3<true, false><<<dim3(196, 9), 256, 0, stream>>>(
      q_w, k_w, v_w, xT, (const uint32_t*)nullptr, (const float*)nullptr,
      yQ, pS, pS2, CDIM, 1152);
  k_bn_reduce3<<<dim3(1152), 64, 0, stream>>>(pS, pS2, mean, rstd, 1152);
  k_lif_pack<true><<<dim3(1152), 256, 0, stream>>>(
      yQ, mean, rstd, q_gamma, k_gamma, v_gamma, q_beta, k_beta, v_beta, pkQKV);

  // 3. attention (exact integer popcount)
  k_attn_pop<<<dim3(BATCH * NHEAD), 256, 0, stream>>>(
      pkQKV, pkQKV + 393216, pkQKV + 786432, pkA);

  // 4. proj GEMM (packed B) + BN + residual -> xres
  k_gemm3<false, true><<<dim3(196, 3), 256, 0, stream>>>(
      proj_w, proj_w, proj_w, (const float*)nullptr, pkA, proj_b,
      yB, pS, pS2, CDIM, 384);
  k_bn_reduce3<<<dim3(384), 64, 0, stream>>>(pS, pS2, mean, rstd, 384);
  k_bn_lif<1><<<dim3(9408), 256, 0, stream>>>(yB, mean, rstd, proj_gamma, proj_beta,
                                              xT, xres);

  // 5. fc1 GEMM (float B = xres)
  k_gemm3<false, false><<<dim3(196, 12), 256, 0, stream>>>(
      fc1_w, fc1_w, fc1_w, xres, (const uint32_t*)nullptr, fc1_b,
      h1, pS, pS2, CDIM, 1536);
  k_bn_reduce3<<<dim3(1536), 64, 0, stream>>>(pS, pS2, mean, rstd, 1536);
  k_lif_pack<false><<<dim3(1536), 256, 0, stream>>>(
      h1, mean, rstd, bn1_gamma, bn1_gamma, bn1_gamma,
      bn1_beta, bn1_beta, bn1_beta, pkH1);

  // 6. fc2 GEMM (packed B, K=1536) + final BN + residual -> out
  k_gemm3<false, true><<<dim3(196, 3), 256, 0, stream>>>(
      fc2_w, fc2_w, fc2_w, (const float*)nullptr, pkH1, fc2_b,
      yB, pS, pS2, HDIM, 384);
  k_bn_reduce3<<<dim3(384), 64, 0, stream>>>(pS, pS2, mean, rstd, 384);
  k_bn_lif<2><<<dim3(9408), 256, 0, stream>>>(yB, mean, rstd, bn2_gamma, bn2_beta,
                                              xres, out);
}

// Round 5
// 1871.416 us; speedup vs baseline: 1.6214x; 1.6214x over previous
//
#include <hip/hip_runtime.h>
#include <stdint.h>

#define NBN   25088   // 128 * 196  (TB * N)
#define NTOK  196
#define BATCH 32
#define CDIM  384
#define HDIM  1536
#define NHEAD 12

// ---------------- transpose: x (TB,C,N) -> xT (C, TB*N) ------------------------
__global__ __launch_bounds__(256) void k_transpose(const float* __restrict__ x,
                                                   float* __restrict__ xT) {
  int id = blockIdx.x * 256 + threadIdx.x;
  int c = id / NBN;
  int r = id - c * NBN;
  int b = r / NTOK;
  int n = r - b * NTOK;
  xT[id] = x[((size_t)b * CDIM + c) * NTOK + n];
}

// ---------------------------------------------------------------------------
// fp32 GEMM, chain-exact (k-ascending fmaf per output), BK=32, no reg
// prefetch (round-1 core), padded B-tile (bank-conflict-free reads),
// fused f64 BN partial sums. B: float (K,NBN) or u8 spikes (K,NBN).
// ---------------------------------------------------------------------------
template <bool QKV, typename TIN>
__global__ __launch_bounds__(256) void k_gemm5(
    const float* __restrict__ W0, const float* __restrict__ W1,
    const float* __restrict__ W2, const TIN* __restrict__ X,
    const float* __restrict__ bias, float* __restrict__ Y,
    double* __restrict__ pS, double* __restrict__ pS2, int K, int Mtot) {
  __shared__ float As[32][133];   // [k][m], stride 133 de-conflicts stage writes
  __shared__ float Bs[32][148];   // [k][padded col]: col c -> c + (c>>5)*4
  const int tid = threadIdx.x;
  const int bn = blockIdx.x, gy = blockIdx.y;
  const float* W;
  int wrow;
  if constexpr (QKV) {
    W = (gy < 3) ? W0 : (gy < 6) ? W1 : W2;
    wrow = (gy % 3) * 128;
  } else {
    W = W0;
    wrow = gy * 128;
  }
  const int orow = gy * 128;
  const int tx = tid & 15, ty = tid >> 4;
  const int NK = K >> 5;
  const int bcr = tx * 8 + ((tx >> 2) << 2);   // padded read base

  float acc[8][8];
#pragma unroll
  for (int i = 0; i < 8; ++i)
#pragma unroll
    for (int j = 0; j < 8; ++j) acc[i][j] = 0.f;

  for (int ks = 0; ks < NK; ++ks) {
    const int k0 = ks << 5;
    // ---- stage A (128 x 32), transposed into [k][m] ----
#pragma unroll
    for (int i = 0; i < 4; ++i) {
      int id2 = tid + i * 256;
      int r = id2 >> 3, c4 = id2 & 7;
      const float4 a = *reinterpret_cast<const float4*>(
          &W[(size_t)(wrow + r) * K + k0 + c4 * 4]);
      As[c4 * 4 + 0][r] = a.x;
      As[c4 * 4 + 1][r] = a.y;
      As[c4 * 4 + 2][r] = a.z;
      As[c4 * 4 + 3][r] = a.w;
    }
    // ---- stage B (32 x 128) with column padding ----
    if constexpr (__is_same(TIN, float)) {
#pragma unroll
      for (int i = 0; i < 4; ++i) {
        int id2 = tid + i * 256;
        int r = id2 >> 5, c4 = id2 & 31;
        const float4 bv = *reinterpret_cast<const float4*>(
            &X[(size_t)(k0 + r) * NBN + bn * 128 + c4 * 4]);
        *reinterpret_cast<float4*>(&Bs[r][c4 * 4 + ((c4 >> 3) << 2)]) = bv;
      }
    } else {
#pragma unroll
      for (int i = 0; i < 2; ++i) {
        int id2 = tid + i * 256;
        int r = id2 >> 4, c8 = id2 & 15;
        const uint2 d = *reinterpret_cast<const uint2*>(
            &X[(size_t)(k0 + r) * NBN + bn * 128 + c8 * 8]);
        const int bc = c8 * 8 + ((c8 >> 2) << 2);
        float4 f0, f1;
        f0.x = (float)(d.x & 0xffu);         f0.y = (float)((d.x >> 8) & 0xffu);
        f0.z = (float)((d.x >> 16) & 0xffu); f0.w = (float)(d.x >> 24);
        f1.x = (float)(d.y & 0xffu);         f1.y = (float)((d.y >> 8) & 0xffu);
        f1.z = (float)((d.y >> 16) & 0xffu); f1.w = (float)(d.y >> 24);
        *reinterpret_cast<float4*>(&Bs[r][bc]) = f0;
        *reinterpret_cast<float4*>(&Bs[r][bc + 4]) = f1;
      }
    }
    __syncthreads();
    // ---- compute: k-ascending fused-FMA chain per output ----
#pragma unroll
    for (int kk = 0; kk < 32; ++kk) {
      float a8[8], b8[8];
      *reinterpret_cast<float4*>(&a8[0]) = *reinterpret_cast<const float4*>(&As[kk][ty * 8]);
      *reinterpret_cast<float4*>(&a8[4]) = *reinterpret_cast<const float4*>(&As[kk][ty * 8 + 4]);
      *reinterpret_cast<float4*>(&b8[0]) = *reinterpret_cast<const float4*>(&Bs[kk][bcr]);
      *reinterpret_cast<float4*>(&b8[4]) = *reinterpret_cast<const float4*>(&Bs[kk][bcr + 4]);
#pragma unroll
      for (int i = 0; i < 8; ++i)
#pragma unroll
        for (int j = 0; j < 8; ++j) acc[i][j] = fmaf(a8[i], b8[j], acc[i][j]);
    }
    __syncthreads();
  }

  // ---- epilogue: bias, store, f64 BN partials ----
#pragma unroll
  for (int i = 0; i < 8; ++i) {
    const int row = orow + ty * 8 + i;
    const float bv = bias ? bias[row] : 0.f;
    float4 o0, o1;
    o0.x = acc[i][0] + bv; o0.y = acc[i][1] + bv;
    o0.z = acc[i][2] + bv; o0.w = acc[i][3] + bv;
    o1.x = acc[i][4] + bv; o1.y = acc[i][5] + bv;
    o1.z = acc[i][6] + bv; o1.w = acc[i][7] + bv;
    *reinterpret_cast<float4*>(&Y[(size_t)row * NBN + bn * 128 + tx * 8]) = o0;
    *reinterpret_cast<float4*>(&Y[(size_t)row * NBN + bn * 128 + tx * 8 + 4]) = o1;
    double s = (double)o0.x + (double)o0.y + (double)o0.z + (double)o0.w +
               (double)o1.x + (double)o1.y + (double)o1.z + (double)o1.w;
    double s2 = (double)o0.x * o0.x + (double)o0.y * o0.y + (double)o0.z * o0.z +
                (double)o0.w * o0.w + (double)o1.x * o1.x + (double)o1.y * o1.y +
                (double)o1.z * o1.z + (double)o1.w * o1.w;
#pragma unroll
    for (int off = 1; off < 16; off <<= 1) {
      s += __shfl_xor(s, off, 64);
      s2 += __shfl_xor(s2, off, 64);
    }
    if (tx == 0) {
      pS[(size_t)bn * Mtot + row] = s;
      pS2[(size_t)bn * Mtot + row] = s2;
    }
  }
}

// ---- BN stat reduce: 196 f64 partials per channel --------------------------
__global__ __launch_bounds__(64) void k_bn_reduce3(const double* __restrict__ pS,
                                                   const double* __restrict__ pS2,
                                                   float* __restrict__ mean,
                                                   float* __restrict__ rstd, int Mtot) {
  const int ch = blockIdx.x, lane = threadIdx.x;
  double s = 0.0, s2 = 0.0;
  for (int j = lane; j < 196; j += 64) {
    s += pS[(size_t)j * Mtot + ch];
    s2 += pS2[(size_t)j * Mtot + ch];
  }
#pragma unroll
  for (int off = 32; off; off >>= 1) {
    s += __shfl_down(s, off, 64);
    s2 += __shfl_down(s2, off, 64);
  }
  if (lane == 0) {
    double m = s / (double)NBN;
    double v = s2 / (double)NBN - m * m;
    mean[ch] = (float)m;
    rstd[ch] = (float)(1.0 / sqrt(v + 1e-5));
  }
}

// ---- BN apply + LIF (thr 1.0) writing PACKED spikes (qkv -> attention) -----
__global__ __launch_bounds__(256) void k_lif_pack(const float* __restrict__ Y,
    const float* __restrict__ mean, const float* __restrict__ rstd,
    const float* __restrict__ g0, const float* __restrict__ g1,
    const float* __restrict__ g2, const float* __restrict__ b0,
    const float* __restrict__ b1, const float* __restrict__ b2,
    uint32_t* __restrict__ pk) {
  const int o = blockIdx.x;
  const int b = threadIdx.x >> 3, w = threadIdx.x & 7;
  int br = o / 384, ol = o - br * 384;
  const float g = (br == 0 ? g0 : br == 1 ? g1 : g2)[ol];
  const float be = (br == 0 ? b0 : br == 1 ? b1 : b2)[ol];
  const float m_ = mean[o], rs_ = rstd[o];
  float mem[32];
#pragma unroll
  for (int j = 0; j < 32; ++j) mem[j] = 0.f;
  for (int t = 0; t < 4; ++t) {
    uint32_t word = 0;
    const size_t base = (size_t)o * NBN + (size_t)(t * 32 + b) * NTOK + w * 32;
#pragma unroll
    for (int q = 0; q < 8; ++q) {
      if (w * 32 + q * 4 < NTOK) {
        float4 v4 = *reinterpret_cast<const float4*>(&Y[base + q * 4]);
        float vv[4] = {v4.x, v4.y, v4.z, v4.w};
#pragma unroll
        for (int jj = 0; jj < 4; ++jj) {
          int j = q * 4 + jj;
          float v = ((vv[jj] - m_) * rs_) * g + be;
          float mm = mem[j];
          mm = mm + (v - mm) * 0.5f;
          bool fire = (mm >= 1.0f);
          mem[j] = fire ? 0.f : mm;
          word |= (fire ? 1u : 0u) << j;
        }
      }
    }
    pk[((size_t)o * 128 + t * 32 + b) * 8 + w] = word;
  }
}

// ---- BN apply + LIF (thr 1.0) writing u8 spikes (fc1 -> fc2 B) -------------
__global__ __launch_bounds__(256) void k_lif_u8(const float* __restrict__ Y,
    const float* __restrict__ mean, const float* __restrict__ rstd,
    const float* __restrict__ gamma, const float* __restrict__ beta,
    uint8_t* __restrict__ sp) {
  const int o = blockIdx.x;
  const int b = threadIdx.x >> 3, w = threadIdx.x & 7;
  const float m_ = mean[o], rs_ = rstd[o], g = gamma[o], be = beta[o];
  float mem[32];
#pragma unroll
  for (int j = 0; j < 32; ++j) mem[j] = 0.f;
  for (int t = 0; t < 4; ++t) {
    const size_t base = (size_t)o * NBN + (size_t)(t * 32 + b) * NTOK + w * 32;
    uint32_t words[8];
#pragma unroll
    for (int q = 0; q < 8; ++q) {
      words[q] = 0;
      if (w * 32 + q * 4 < NTOK) {
        float4 v4 = *reinterpret_cast<const float4*>(&Y[base + q * 4]);
        float vv[4] = {v4.x, v4.y, v4.z, v4.w};
#pragma unroll
        for (int jj = 0; jj < 4; ++jj) {
          int j = q * 4 + jj;
          float v = ((vv[jj] - m_) * rs_) * g + be;
          float mm = mem[j];
          mm = mm + (v - mm) * 0.5f;
          bool fire = (mm >= 1.0f);
          mem[j] = fire ? 0.f : mm;
          words[q] |= (fire ? 1u : 0u) << (8 * jj);
        }
      }
    }
    uint32_t* dst = reinterpret_cast<uint32_t*>(
        const_cast<uint8_t*>(sp) + base);
#pragma unroll
    for (int q = 0; q < 8; ++q)
      if (w * 32 + q * 4 < NTOK) dst[q] = words[q];
  }
}

// ---- BN apply + LIF, float outputs -----------------------------------------
// MODE 1: xres(C,NBN) = xT + spike.  MODE 2: out(TB,C,N) = xres + spike.
template <int MODE>
__global__ __launch_bounds__(256) void k_bn_lif(const float* __restrict__ Y,
                                                const float* __restrict__ mean,
                                                const float* __restrict__ rstd,
                                                const float* __restrict__ gamma,
                                                const float* __restrict__ beta,
                                                const float* __restrict__ addsrc,
                                                float* __restrict__ extra) {
  int id = blockIdx.x * 256 + threadIdx.x;
  int o = id / (BATCH * NTOK);
  int r = id - o * (BATCH * NTOK);
  float m_ = mean[o], rs_ = rstd[o], g = gamma[o], be = beta[o];
  float mem = 0.f;
#pragma unroll
  for (int t = 0; t < 4; ++t) {
    size_t idx = (size_t)o * NBN + (size_t)t * (BATCH * NTOK) + r;
    float v = Y[idx];
    v = ((v - m_) * rs_) * g + be;
    mem = mem + (v - mem) * 0.5f;
    bool fire = (mem >= 1.0f);
    float s = fire ? 1.f : 0.f;
    mem = fire ? 0.f : mem;
    if constexpr (MODE == 1) {
      extra[idx] = addsrc[idx] + s;
    } else {
      int b = r / NTOK, n = r - b * NTOK;
      extra[((size_t)(t * BATCH + b) * CDIM + o) * NTOK + n] = addsrc[idx] + s;
    }
  }
}

// ---- attention via popcount (exact integers), u8 output --------------------
__global__ __launch_bounds__(256) void k_attn_pop(const uint32_t* __restrict__ pQ,
                                                  const uint32_t* __restrict__ pK,
                                                  const uint32_t* __restrict__ pV,
                                                  uint8_t* __restrict__ spA) {
  __shared__ __align__(16) uint32_t qw[32][8], kw[32][8], vw[32][8];
  __shared__ int kv[32][33];
  __shared__ uint32_t kvb[8][32];
  __shared__ uint32_t qT[NTOK];
  const int bh = blockIdx.x;
  const int b_ = bh / NHEAD, h = bh - b_ * NHEAD;
  const int tid = threadIdx.x;
  const int e = tid >> 3, w = tid & 7;
  float mem[32];
#pragma unroll
  for (int j = 0; j < 32; ++j) mem[j] = 0.f;

  for (int t = 0; t < 4; ++t) {
    const int tb = t * 32 + b_;
    {
      int d = tid >> 3, wo = tid & 7;
      size_t base = ((size_t)(h * 32 + d) * 128 + tb) * 8 + wo;
      qw[d][wo] = pQ[base];
      kw[d][wo] = pK[base];
      vw[d][wo] = pV[base];
    }
    __syncthreads();
    for (int i = tid; i < 1024; i += 256) {
      int d = i >> 5, ee = i & 31;
      const uint64_t* kp = reinterpret_cast<const uint64_t*>(&kw[d][0]);
      const uint64_t* vp = reinterpret_cast<const uint64_t*>(&vw[ee][0]);
      int s = 0;
#pragma unroll
      for (int u = 0; u < 4; ++u) s += __popcll(kp[u] & vp[u]);
      kv[d][ee] = s;
    }
    __syncthreads();
    {
      int bitb = tid >> 5, ee = tid & 31;
      uint32_t mword = 0;
#pragma unroll
      for (int d = 0; d < 32; ++d) mword |= (uint32_t)((kv[d][ee] >> bitb) & 1) << d;
      kvb[bitb][ee] = mword;
    }
    if (tid < NTOK) {
      uint32_t mword = 0;
#pragma unroll
      for (int d = 0; d < 32; ++d)
        mword |= ((qw[d][tid >> 5] >> (tid & 31)) & 1u) << d;
      qT[tid] = mword;
    }
    __syncthreads();
    uint32_t word = 0;
#pragma unroll
    for (int j = 0; j < 32; ++j) {
      int n = w * 32 + j;
      if (n < NTOK) {
        uint32_t qm = qT[n];
        int acc = 0;
#pragma unroll
        for (int bb = 0; bb < 8; ++bb) acc += __popc(qm & kvb[bb][e]) << bb;
        float val = (float)acc * 0.125f;
        float mm = mem[j];
        mm = mm + (val - mm) * 0.5f;
        bool fire = (mm >= 0.5f);
        mem[j] = fire ? 0.f : mm;
        word |= (fire ? 1u : 0u) << j;
      }
    }
    uint8_t* dst = spA + (size_t)(h * 32 + e) * NBN + (size_t)tb * NTOK + w * 32;
#pragma unroll
    for (int q = 0; q < 8; ++q) {
      if (w * 32 + q * 4 < NTOK) {
        uint32_t b4 = ((word >> (q * 4)) & 1u) | (((word >> (q * 4 + 1)) & 1u) << 8) |
                      (((word >> (q * 4 + 2)) & 1u) << 16) |
                      (((word >> (q * 4 + 3)) & 1u) << 24);
        *reinterpret_cast<uint32_t*>(dst + q * 4) = b4;
      }
    }
    __syncthreads();
  }
}

// ---------------------------------------------------------------------------
extern "C" void kernel_launch(void* const* d_in, const int* in_sizes, int n_in,
                              void* d_out, int out_size, void* d_ws, size_t ws_size,
                              hipStream_t stream) {
  const float* x          = (const float*)d_in[0];
  const float* q_w        = (const float*)d_in[1];
  const float* q_gamma    = (const float*)d_in[2];
  const float* q_beta     = (const float*)d_in[3];
  const float* k_w        = (const float*)d_in[4];
  const float* k_gamma    = (const float*)d_in[5];
  const float* k_beta     = (const float*)d_in[6];
  const float* v_w        = (const float*)d_in[7];
  const float* v_gamma    = (const float*)d_in[8];
  const float* v_beta     = (const float*)d_in[9];
  const float* proj_w     = (const float*)d_in[10];
  const float* proj_b     = (const float*)d_in[11];
  const float* proj_gamma = (const float*)d_in[12];
  const float* proj_beta  = (const float*)d_in[13];
  const float* fc1_w      = (const float*)d_in[14];
  const float* fc1_b      = (const float*)d_in[15];
  const float* bn1_gamma  = (const float*)d_in[16];
  const float* bn1_beta   = (const float*)d_in[17];
  const float* fc2_w      = (const float*)d_in[18];
  const float* fc2_b      = (const float*)d_in[19];
  const float* bn2_gamma  = (const float*)d_in[20];
  const float* bn2_beta   = (const float*)d_in[21];
  float* out = (float*)d_out;
  char* ws = (char*)d_ws;

  // ---- arena (bytes); peak 231,211,008 = round-1-proven footprint ----
  const size_t O_XT   = 0;           // xT f32 (384,NBN)   38,535,168; fc1: h1 overlay n/a
  const size_t O_YQ   = 38535168;    // yQKV f32 (1152,NBN) 115,605,504; yB/h1chunk first 38.5M
  const size_t O_XRES = 154140672;   // xres f32 (384,NBN)  38,535,168; P1 partials pre-xres
  const size_t O_SPK  = 192675840;   // packed qkv bits      4,718,592; later h1sp overlay
  const size_t O_SPA  = 197394432;   // attn u8 spikes       9,633,792
  const size_t O_H1SP = 192675840;   // u8 (1536,NBN)       38,535,168  (after attn+proj dead)
  // per-stage scratch (lifetime-verified):
  const size_t P1S  = O_XRES;                 // qkv/proj partials (consumed before xres write)
  const size_t P1S2 = P1S + 1806336;
  const size_t ST1  = 207028224;              // qkv/proj mean/rstd (h1sp region, not yet live)
  const size_t P2S  = 77070336;               // fc1/fc2 partials (yQ tail, dead after qkv)
  const size_t P2S2 = P2S + 602112;
  const size_t ST2  = P2S2 + 602112;          // fc1/fc2 mean/rstd

  float* xT    = (float*)(ws + O_XT);
  float* yQ    = (float*)(ws + O_YQ);
  float* yB    = (float*)(ws + O_YQ);
  float* xres  = (float*)(ws + O_XRES);
  uint32_t* pkQKV = (uint32_t*)(ws + O_SPK);
  uint8_t* spA   = (uint8_t*)(ws + O_SPA);
  uint8_t* h1sp  = (uint8_t*)(ws + O_H1SP);
  double* p1S  = (double*)(ws + P1S);
  double* p1S2 = (double*)(ws + P1S2);
  float* mean1 = (float*)(ws + ST1);
  float* rstd1 = (float*)(ws + ST1 + 4608);
  double* p2S  = (double*)(ws + P2S);
  double* p2S2 = (double*)(ws + P2S2);
  float* mean2 = (float*)(ws + ST2);
  float* rstd2 = (float*)(ws + ST2 + 1536);

  // 1. transpose
  k_transpose<<<dim3(CDIM * NBN / 256), 256, 0, stream>>>(x, xT);

  // 2. fused q/k/v GEMM (chain-exact) + BN partials + packed LIF
  k_gemm5<true, float><<<dim3(196, 9), 256, 0, stream>>>(
      q_w, k_w, v_w, xT, (const float*)nullptr, yQ, p1S, p1S2, CDIM, 1152);
  k_bn_reduce3<<<dim3(1152), 64, 0, stream>>>(p1S, p1S2, mean1, rstd1, 1152);
  k_lif_pack<<<dim3(1152), 256, 0, stream>>>(
      yQ, mean1, rstd1, q_gamma, k_gamma, v_gamma, q_beta, k_beta, v_beta, pkQKV);

  // 3. attention (exact integer popcount) -> u8 spikes
  k_attn_pop<<<dim3(BATCH * NHEAD), 256, 0, stream>>>(
      pkQKV, pkQKV + 393216, pkQKV + 786432, spA);

  // 4. proj GEMM (u8 B) + BN + residual -> xres
  k_gemm5<false, uint8_t><<<dim3(196, 3), 256, 0, stream>>>(
      proj_w, proj_w, proj_w, spA, proj_b, yB, p1S, p1S2, CDIM, 384);
  k_bn_reduce3<<<dim3(384), 64, 0, stream>>>(p1S, p1S2, mean1, rstd1, 384);
  k_bn_lif<1><<<dim3(9408), 256, 0, stream>>>(yB, mean1, rstd1, proj_gamma, proj_beta,
                                              xT, xres);

  // 5. fc1 GEMM (float B = xres), 4 chunks of M=384 -> u8 spikes
  for (int c = 0; c < 4; ++c) {
    k_gemm5<false, float><<<dim3(196, 3), 256, 0, stream>>>(
        fc1_w + (size_t)c * 384 * CDIM, nullptr, nullptr, xres,
        fc1_b + c * 384, yB, p2S, p2S2, CDIM, 384);
    k_bn_reduce3<<<dim3(384), 64, 0, stream>>>(p2S, p2S2, mean2, rstd2, 384);
    k_lif_u8<<<dim3(384), 256, 0, stream>>>(yB, mean2, rstd2,
        bn1_gamma + c * 384, bn1_beta + c * 384, h1sp + (size_t)c * 384 * NBN);
  }

  // 6. fc2 GEMM (u8 B, K=1536) + final BN + residual -> out
  k_gemm5<false, uint8_t><<<dim3(196, 3), 256, 0, stream>>>(
      fc2_w, fc2_w, fc2_w, h1sp, fc2_b, yB, p2S, p2S2, HDIM, 384);
  k_bn_reduce3<<<dim3(384), 64, 0, stream>>>(p2S, p2S2, mean2, rstd2, 384);
  k_bn_lif<2><<<dim3(9408), 256, 0, stream>>>(yB, mean2, rstd2, bn2_gamma, bn2_beta,
                                              xres, out);
}

// Round 6
// 1351.815 us; speedup vs baseline: 2.2446x; 1.3844x over previous
//
#include <hip/hip_runtime.h>
#include <stdint.h>

#define NBN   25088   // 128 * 196  (TB * N)
#define NTOK  196
#define BATCH 32
#define CDIM  384
#define HDIM  1536
#define NHEAD 12

// ---------------- transpose: x (TB,C,N) -> xT (C, TB*N) ------------------------
__global__ __launch_bounds__(256) void k_transpose(const float* __restrict__ x,
                                                   float* __restrict__ xT) {
  int id = blockIdx.x * 256 + threadIdx.x;
  int c = id / NBN;
  int r = id - c * NBN;
  int b = r / NTOK;
  int n = r - b * NTOK;
  xT[id] = x[((size_t)b * CDIM + c) * NTOK + n];
}

// ---------------------------------------------------------------------------
// fp32 GEMM, chain-exact (k-ascending fmaf per output). Round-1 geometry:
// BK=16, As[16][132] ([k][m]), Bs[16][132], 8x8 microtile. Fragment reads
// split into two float4 halves at t*4 and 64+t*4 -> 2-way banks (free),
// 16B-aligned ds_read_b128 preserved. Fused f64 BN partial sums.
// ---------------------------------------------------------------------------
template <bool QKV, typename TIN>
__global__ __launch_bounds__(256, 4) void k_gemm6(
    const float* __restrict__ W0, const float* __restrict__ W1,
    const float* __restrict__ W2, const TIN* __restrict__ X,
    const float* __restrict__ bias, float* __restrict__ Y,
    double* __restrict__ pS, double* __restrict__ pS2, int K, int Mtot) {
  __shared__ float As[16][132];
  __shared__ float Bs[16][132];
  const int tid = threadIdx.x;
  const int bn = blockIdx.x, gy = blockIdx.y;
  const float* W;
  int wrow;
  if constexpr (QKV) {
    W = (gy < 3) ? W0 : (gy < 6) ? W1 : W2;
    wrow = (gy % 3) * 128;
  } else {
    W = W0;
    wrow = gy * 128;
  }
  const int orow = gy * 128;
  const int tx = tid & 15, ty = tid >> 4;
  const int NK = K >> 4;

  float acc[8][8];
#pragma unroll
  for (int i = 0; i < 8; ++i)
#pragma unroll
    for (int j = 0; j < 8; ++j) acc[i][j] = 0.f;

  for (int ks = 0; ks < NK; ++ks) {
    const int k0 = ks << 4;
    // ---- stage A (128 rows x 16 k), transposed to [k][m] ----
#pragma unroll
    for (int i = 0; i < 2; ++i) {
      int id2 = tid + i * 256;
      int r = id2 >> 2, c4 = id2 & 3;
      const float4 a = *reinterpret_cast<const float4*>(
          &W[(size_t)(wrow + r) * K + k0 + c4 * 4]);
      As[c4 * 4 + 0][r] = a.x;
      As[c4 * 4 + 1][r] = a.y;
      As[c4 * 4 + 2][r] = a.z;
      As[c4 * 4 + 3][r] = a.w;
    }
    // ---- stage B (16 k x 128 cols) ----
    if constexpr (__is_same(TIN, float)) {
#pragma unroll
      for (int i = 0; i < 2; ++i) {
        int id2 = tid + i * 256;
        int r = id2 >> 5, c4 = id2 & 31;
        const float4 bv = *reinterpret_cast<const float4*>(
            &X[(size_t)(k0 + r) * NBN + bn * 128 + c4 * 4]);
        *reinterpret_cast<float4*>(&Bs[r][c4 * 4]) = bv;
      }
    } else {
      int r = tid >> 4, c8 = tid & 15;
      const uint2 d = *reinterpret_cast<const uint2*>(
          &X[(size_t)(k0 + r) * NBN + bn * 128 + c8 * 8]);
      float4 f0, f1;
      f0.x = (float)(d.x & 0xffu);         f0.y = (float)((d.x >> 8) & 0xffu);
      f0.z = (float)((d.x >> 16) & 0xffu); f0.w = (float)(d.x >> 24);
      f1.x = (float)(d.y & 0xffu);         f1.y = (float)((d.y >> 8) & 0xffu);
      f1.z = (float)((d.y >> 16) & 0xffu); f1.w = (float)(d.y >> 24);
      *reinterpret_cast<float4*>(&Bs[r][c8 * 8]) = f0;
      *reinterpret_cast<float4*>(&Bs[r][c8 * 8 + 4]) = f1;
    }
    __syncthreads();
    // ---- compute: k-ascending fused-FMA chain per output ----
#pragma unroll
    for (int kk = 0; kk < 16; ++kk) {
      float a8[8], b8[8];
      *reinterpret_cast<float4*>(&a8[0]) = *reinterpret_cast<const float4*>(&As[kk][ty * 4]);
      *reinterpret_cast<float4*>(&a8[4]) = *reinterpret_cast<const float4*>(&As[kk][64 + ty * 4]);
      *reinterpret_cast<float4*>(&b8[0]) = *reinterpret_cast<const float4*>(&Bs[kk][tx * 4]);
      *reinterpret_cast<float4*>(&b8[4]) = *reinterpret_cast<const float4*>(&Bs[kk][64 + tx * 4]);
#pragma unroll
      for (int i = 0; i < 8; ++i)
#pragma unroll
        for (int j = 0; j < 8; ++j) acc[i][j] = fmaf(a8[i], b8[j], acc[i][j]);
    }
    __syncthreads();
  }

  // ---- epilogue: bias, store, f64 BN partials ----
  // row map: i<4 -> ty*4+i ; i>=4 -> 64+ty*4+(i-4)
  // col map: j<4 -> tx*4+j ; j>=4 -> 64+tx*4+(j-4)
#pragma unroll
  for (int i = 0; i < 8; ++i) {
    const int rl = (i < 4) ? (ty * 4 + i) : (64 + ty * 4 + i - 4);
    const int row = orow + rl;
    const float bv = bias ? bias[row] : 0.f;
    float4 o0, o1;
    o0.x = acc[i][0] + bv; o0.y = acc[i][1] + bv;
    o0.z = acc[i][2] + bv; o0.w = acc[i][3] + bv;
    o1.x = acc[i][4] + bv; o1.y = acc[i][5] + bv;
    o1.z = acc[i][6] + bv; o1.w = acc[i][7] + bv;
    *reinterpret_cast<float4*>(&Y[(size_t)row * NBN + bn * 128 + tx * 4]) = o0;
    *reinterpret_cast<float4*>(&Y[(size_t)row * NBN + bn * 128 + 64 + tx * 4]) = o1;
    double s = (double)o0.x + (double)o0.y + (double)o0.z + (double)o0.w +
               (double)o1.x + (double)o1.y + (double)o1.z + (double)o1.w;
    double s2 = (double)o0.x * o0.x + (double)o0.y * o0.y + (double)o0.z * o0.z +
                (double)o0.w * o0.w + (double)o1.x * o1.x + (double)o1.y * o1.y +
                (double)o1.z * o1.z + (double)o1.w * o1.w;
#pragma unroll
    for (int off = 1; off < 16; off <<= 1) {
      s += __shfl_xor(s, off, 64);
      s2 += __shfl_xor(s2, off, 64);
    }
    if (tx == 0) {
      pS[(size_t)bn * Mtot + row] = s;
      pS2[(size_t)bn * Mtot + row] = s2;
    }
  }
}

// ---- BN stat reduce: 196 f64 partials per channel --------------------------
__global__ __launch_bounds__(64) void k_bn_reduce3(const double* __restrict__ pS,
                                                   const double* __restrict__ pS2,
                                                   float* __restrict__ mean,
                                                   float* __restrict__ rstd, int Mtot) {
  const int ch = blockIdx.x, lane = threadIdx.x;
  double s = 0.0, s2 = 0.0;
  for (int j = lane; j < 196; j += 64) {
    s += pS[(size_t)j * Mtot + ch];
    s2 += pS2[(size_t)j * Mtot + ch];
  }
#pragma unroll
  for (int off = 32; off; off >>= 1) {
    s += __shfl_down(s, off, 64);
    s2 += __shfl_down(s2, off, 64);
  }
  if (lane == 0) {
    double m = s / (double)NBN;
    double v = s2 / (double)NBN - m * m;
    mean[ch] = (float)m;
    rstd[ch] = (float)(1.0 / sqrt(v + 1e-5));
  }
}

// ---- BN apply + LIF (thr 1.0) writing PACKED spikes (qkv -> attention) -----
__global__ __launch_bounds__(256) void k_lif_pack(const float* __restrict__ Y,
    const float* __restrict__ mean, const float* __restrict__ rstd,
    const float* __restrict__ g0, const float* __restrict__ g1,
    const float* __restrict__ g2, const float* __restrict__ b0,
    const float* __restrict__ b1, const float* __restrict__ b2,
    uint32_t* __restrict__ pk) {
  const int o = blockIdx.x;
  const int b = threadIdx.x >> 3, w = threadIdx.x & 7;
  int br = o / 384, ol = o - br * 384;
  const float g = (br == 0 ? g0 : br == 1 ? g1 : g2)[ol];
  const float be = (br == 0 ? b0 : br == 1 ? b1 : b2)[ol];
  const float m_ = mean[o], rs_ = rstd[o];
  float mem[32];
#pragma unroll
  for (int j = 0; j < 32; ++j) mem[j] = 0.f;
  for (int t = 0; t < 4; ++t) {
    uint32_t word = 0;
    const size_t base = (size_t)o * NBN + (size_t)(t * 32 + b) * NTOK + w * 32;
#pragma unroll
    for (int q = 0; q < 8; ++q) {
      if (w * 32 + q * 4 < NTOK) {
        float4 v4 = *reinterpret_cast<const float4*>(&Y[base + q * 4]);
        float vv[4] = {v4.x, v4.y, v4.z, v4.w};
#pragma unroll
        for (int jj = 0; jj < 4; ++jj) {
          int j = q * 4 + jj;
          float v = ((vv[jj] - m_) * rs_) * g + be;
          float mm = mem[j];
          mm = mm + (v - mm) * 0.5f;
          bool fire = (mm >= 1.0f);
          mem[j] = fire ? 0.f : mm;
          word |= (fire ? 1u : 0u) << j;
        }
      }
    }
    pk[((size_t)o * 128 + t * 32 + b) * 8 + w] = word;
  }
}

// ---- BN apply + LIF (thr 1.0) writing u8 spikes (fc1 -> fc2 B) -------------
__global__ __launch_bounds__(256) void k_lif_u8(const float* __restrict__ Y,
    const float* __restrict__ mean, const float* __restrict__ rstd,
    const float* __restrict__ gamma, const float* __restrict__ beta,
    uint8_t* __restrict__ sp) {
  const int o = blockIdx.x;
  const int b = threadIdx.x >> 3, w = threadIdx.x & 7;
  const float m_ = mean[o], rs_ = rstd[o], g = gamma[o], be = beta[o];
  float mem[32];
#pragma unroll
  for (int j = 0; j < 32; ++j) mem[j] = 0.f;
  for (int t = 0; t < 4; ++t) {
    const size_t base = (size_t)o * NBN + (size_t)(t * 32 + b) * NTOK + w * 32;
    uint32_t words[8];
#pragma unroll
    for (int q = 0; q < 8; ++q) {
      words[q] = 0;
      if (w * 32 + q * 4 < NTOK) {
        float4 v4 = *reinterpret_cast<const float4*>(&Y[base + q * 4]);
        float vv[4] = {v4.x, v4.y, v4.z, v4.w};
#pragma unroll
        for (int jj = 0; jj < 4; ++jj) {
          int j = q * 4 + jj;
          float v = ((vv[jj] - m_) * rs_) * g + be;
          float mm = mem[j];
          mm = mm + (v - mm) * 0.5f;
          bool fire = (mm >= 1.0f);
          mem[j] = fire ? 0.f : mm;
          words[q] |= (fire ? 1u : 0u) << (8 * jj);
        }
      }
    }
    uint32_t* dst = reinterpret_cast<uint32_t*>(const_cast<uint8_t*>(sp) + base);
#pragma unroll
    for (int q = 0; q < 8; ++q)
      if (w * 32 + q * 4 < NTOK) dst[q] = words[q];
  }
}

// ---- BN apply + LIF, float outputs -----------------------------------------
// MODE 1: xres(C,NBN) = xT + spike.  MODE 2: out(TB,C,N) = xres + spike.
template <int MODE>
__global__ __launch_bounds__(256) void k_bn_lif(const float* __restrict__ Y,
                                                const float* __restrict__ mean,
                                                const float* __restrict__ rstd,
                                                const float* __restrict__ gamma,
                                                const float* __restrict__ beta,
                                                const float* __restrict__ addsrc,
                                                float* __restrict__ extra) {
  int id = blockIdx.x * 256 + threadIdx.x;
  int o = id / (BATCH * NTOK);
  int r = id - o * (BATCH * NTOK);
  float m_ = mean[o], rs_ = rstd[o], g = gamma[o], be = beta[o];
  float mem = 0.f;
#pragma unroll
  for (int t = 0; t < 4; ++t) {
    size_t idx = (size_t)o * NBN + (size_t)t * (BATCH * NTOK) + r;
    float v = Y[idx];
    v = ((v - m_) * rs_) * g + be;
    mem = mem + (v - mem) * 0.5f;
    bool fire = (mem >= 1.0f);
    float s = fire ? 1.f : 0.f;
    mem = fire ? 0.f : mem;
    if constexpr (MODE == 1) {
      extra[idx] = addsrc[idx] + s;
    } else {
      int b = r / NTOK, n = r - b * NTOK;
      extra[((size_t)(t * BATCH + b) * CDIM + o) * NTOK + n] = addsrc[idx] + s;
    }
  }
}

// ---- attention via popcount (exact integers), u8 output --------------------
__global__ __launch_bounds__(256) void k_attn_pop(const uint32_t* __restrict__ pQ,
                                                  const uint32_t* __restrict__ pK,
                                                  const uint32_t* __restrict__ pV,
                                                  uint8_t* __restrict__ spA) {
  __shared__ __align__(16) uint32_t qw[32][8], kw[32][8], vw[32][8];
  __shared__ int kv[32][33];
  __shared__ uint32_t kvb[8][32];
  __shared__ uint32_t qT[NTOK];
  const int bh = blockIdx.x;
  const int b_ = bh / NHEAD, h = bh - b_ * NHEAD;
  const int tid = threadIdx.x;
  const int e = tid >> 3, w = tid & 7;
  float mem[32];
#pragma unroll
  for (int j = 0; j < 32; ++j) mem[j] = 0.f;

  for (int t = 0; t < 4; ++t) {
    const int tb = t * 32 + b_;
    {
      int d = tid >> 3, wo = tid & 7;
      size_t base = ((size_t)(h * 32 + d) * 128 + tb) * 8 + wo;
      qw[d][wo] = pQ[base];
      kw[d][wo] = pK[base];
      vw[d][wo] = pV[base];
    }
    __syncthreads();
    for (int i = tid; i < 1024; i += 256) {
      int d = i >> 5, ee = i & 31;
      const uint64_t* kp = reinterpret_cast<const uint64_t*>(&kw[d][0]);
      const uint64_t* vp = reinterpret_cast<const uint64_t*>(&vw[ee][0]);
      int s = 0;
#pragma unroll
      for (int u = 0; u < 4; ++u) s += __popcll(kp[u] & vp[u]);
      kv[d][ee] = s;
    }
    __syncthreads();
    {
      int bitb = tid >> 5, ee = tid & 31;
      uint32_t mword = 0;
#pragma unroll
      for (int d = 0; d < 32; ++d) mword |= (uint32_t)((kv[d][ee] >> bitb) & 1) << d;
      kvb[bitb][ee] = mword;
    }
    if (tid < NTOK) {
      uint32_t mword = 0;
#pragma unroll
      for (int d = 0; d < 32; ++d)
        mword |= ((qw[d][tid >> 5] >> (tid & 31)) & 1u) << d;
      qT[tid] = mword;
    }
    __syncthreads();
    uint32_t word = 0;
#pragma unroll
    for (int j = 0; j < 32; ++j) {
      int n = w * 32 + j;
      if (n < NTOK) {
        uint32_t qm = qT[n];
        int acc = 0;
#pragma unroll
        for (int bb = 0; bb < 8; ++bb) acc += __popc(qm & kvb[bb][e]) << bb;
        float val = (float)acc * 0.125f;
        float mm = mem[j];
        mm = mm + (val - mm) * 0.5f;
        bool fire = (mm >= 0.5f);
        mem[j] = fire ? 0.f : mm;
        word |= (fire ? 1u : 0u) << j;
      }
    }
    uint8_t* dst = spA + (size_t)(h * 32 + e) * NBN + (size_t)tb * NTOK + w * 32;
#pragma unroll
    for (int q = 0; q < 8; ++q) {
      if (w * 32 + q * 4 < NTOK) {
        uint32_t b4 = ((word >> (q * 4)) & 1u) | (((word >> (q * 4 + 1)) & 1u) << 8) |
                      (((word >> (q * 4 + 2)) & 1u) << 16) |
                      (((word >> (q * 4 + 3)) & 1u) << 24);
        *reinterpret_cast<uint32_t*>(dst + q * 4) = b4;
      }
    }
    __syncthreads();
  }
}

// ---------------------------------------------------------------------------
extern "C" void kernel_launch(void* const* d_in, const int* in_sizes, int n_in,
                              void* d_out, int out_size, void* d_ws, size_t ws_size,
                              hipStream_t stream) {
  const float* x          = (const float*)d_in[0];
  const float* q_w        = (const float*)d_in[1];
  const float* q_gamma    = (const float*)d_in[2];
  const float* q_beta     = (const float*)d_in[3];
  const float* k_w        = (const float*)d_in[4];
  const float* k_gamma    = (const float*)d_in[5];
  const float* k_beta     = (const float*)d_in[6];
  const float* v_w        = (const float*)d_in[7];
  const float* v_gamma    = (const float*)d_in[8];
  const float* v_beta     = (const float*)d_in[9];
  const float* proj_w     = (const float*)d_in[10];
  const float* proj_b     = (const float*)d_in[11];
  const float* proj_gamma = (const float*)d_in[12];
  const float* proj_beta  = (const float*)d_in[13];
  const float* fc1_w      = (const float*)d_in[14];
  const float* fc1_b      = (const float*)d_in[15];
  const float* bn1_gamma  = (const float*)d_in[16];
  const float* bn1_beta   = (const float*)d_in[17];
  const float* fc2_w      = (const float*)d_in[18];
  const float* fc2_b      = (const float*)d_in[19];
  const float* bn2_gamma  = (const float*)d_in[20];
  const float* bn2_beta   = (const float*)d_in[21];
  float* out = (float*)d_out;
  char* ws = (char*)d_ws;

  // ---- arena (bytes); peak 231,220,224 <= round-1-proven 231,223,296 ----
  const size_t O_XT   = 0;            // xT f32 (384,NBN)          38,535,168
  const size_t O_YQ   = 38535168;     // yQKV (1152,NBN) / proj yB
  const size_t O_P1   = 154140672;    // qkv/proj f64 partials (pre-xres)
  const size_t O_P1B  = 155947008;
  const size_t O_XRES = 154140672;    // xres f32 (384,NBN), after P1 dead
  const size_t O_PK   = 192675840;    // packed qkv bits 4,718,592
  const size_t O_SPA  = 197394432;    // attn u8 spikes  9,633,792
  const size_t O_H1SP = 192675840;    // u8 (1536,NBN) 38,535,168 (fc1 stage)
  const size_t O_H1C  = 0;            // fc1 chunk f32 (768,NBN) 77,070,336
  const size_t O_P2   = 77070336;     // fc1/fc2 f64 partials
  const size_t O_P2B  = 78274560;
  const size_t O_ST   = 231211008;    // mean/rstd (<= 1152 ch)

  float* xT    = (float*)(ws + O_XT);
  float* yQ    = (float*)(ws + O_YQ);
  float* yB    = (float*)(ws + O_YQ);
  float* h1c   = (float*)(ws + O_H1C);
  float* xres  = (float*)(ws + O_XRES);
  uint32_t* pkQKV = (uint32_t*)(ws + O_PK);
  uint8_t* spA   = (uint8_t*)(ws + O_SPA);
  uint8_t* h1sp  = (uint8_t*)(ws + O_H1SP);
  double* p1S  = (double*)(ws + O_P1);
  double* p1S2 = (double*)(ws + O_P1B);
  double* p2S  = (double*)(ws + O_P2);
  double* p2S2 = (double*)(ws + O_P2B);
  float* mean_ = (float*)(ws + O_ST);
  float* rstd_ = (float*)(ws + O_ST + 4608);

  // 1. transpose
  k_transpose<<<dim3(CDIM * NBN / 256), 256, 0, stream>>>(x, xT);

  // 2. fused q/k/v GEMM (chain-exact) + BN partials + packed LIF
  k_gemm6<true, float><<<dim3(196, 9), 256, 0, stream>>>(
      q_w, k_w, v_w, xT, (const float*)nullptr, yQ, p1S, p1S2, CDIM, 1152);
  k_bn_reduce3<<<dim3(1152), 64, 0, stream>>>(p1S, p1S2, mean_, rstd_, 1152);
  k_lif_pack<<<dim3(1152), 256, 0, stream>>>(
      yQ, mean_, rstd_, q_gamma, k_gamma, v_gamma, q_beta, k_beta, v_beta, pkQKV);

  // 3. attention (exact integer popcount) -> u8 spikes
  k_attn_pop<<<dim3(BATCH * NHEAD), 256, 0, stream>>>(
      pkQKV, pkQKV + 393216, pkQKV + 786432, spA);

  // 4. proj GEMM (u8 B) + BN + residual -> xres
  k_gemm6<false, uint8_t><<<dim3(196, 3), 256, 0, stream>>>(
      proj_w, proj_w, proj_w, spA, proj_b, yB, p1S, p1S2, CDIM, 384);
  k_bn_reduce3<<<dim3(384), 64, 0, stream>>>(p1S, p1S2, mean_, rstd_, 384);
  k_bn_lif<1><<<dim3(9408), 256, 0, stream>>>(yB, mean_, rstd_, proj_gamma, proj_beta,
                                              xT, xres);

  // 5. fc1 GEMM (float B = xres), 2 chunks of M=768 -> u8 spikes
  for (int c = 0; c < 2; ++c) {
    k_gemm6<false, float><<<dim3(196, 6), 256, 0, stream>>>(
        fc1_w + (size_t)c * 768 * CDIM, nullptr, nullptr, xres,
        fc1_b + c * 768, h1c, p2S, p2S2, CDIM, 768);
    k_bn_reduce3<<<dim3(768), 64, 0, stream>>>(p2S, p2S2, mean_, rstd_, 768);
    k_lif_u8<<<dim3(768), 256, 0, stream>>>(h1c, mean_, rstd_,
        bn1_gamma + c * 768, bn1_beta + c * 768, h1sp + (size_t)c * 768 * NBN);
  }

  // 6. fc2 GEMM (u8 B, K=1536) + final BN + residual -> out
  k_gemm6<false, uint8_t><<<dim3(196, 3), 256, 0, stream>>>(
      fc2_w, fc2_w, fc2_w, h1sp, fc2_b, yB, p2S, p2S2, HDIM, 384);
  k_bn_reduce3<<<dim3(384), 64, 0, stream>>>(p2S, p2S2, mean_, rstd_, 384);
  k_bn_lif<2><<<dim3(9408), 256, 0, stream>>>(yB, mean_, rstd_, bn2_gamma, bn2_beta,
                                              xres, out);
}

// Round 7
// 1341.574 us; speedup vs baseline: 2.2617x; 1.0076x over previous
//
#include <hip/hip_runtime.h>
#include <stdint.h>

#define NBN   25088   // 128 * 196  (TB * N)
#define NTOK  196
#define BATCH 32
#define CDIM  384
#define HDIM  1536
#define NHEAD 12

#define GLDS16(g, l) __builtin_amdgcn_global_load_lds( \
    (const __attribute__((address_space(1))) void*)(g), \
    (__attribute__((address_space(3))) void*)(l), 16, 0, 0)

// ---------------- transpose: x (TB,C,N) -> xT (C, TB*N) ------------------------
__global__ __launch_bounds__(256) void k_transpose(const float* __restrict__ x,
                                                   float* __restrict__ xT) {
  int id = blockIdx.x * 256 + threadIdx.x;
  int c = id / NBN;
  int r = id - c * NBN;
  int b = r / NTOK;
  int n = r - b * NTOK;
  xT[id] = x[((size_t)b * CDIM + c) * NTOK + n];
}

// ---- weight transpose: src (R,C) -> dst[c*ldd + coff + r], grid (C/32, R/32) --
__global__ __launch_bounds__(256) void k_wT(const float* __restrict__ src,
                                            float* __restrict__ dst,
                                            int C, int ldd, int coff) {
  __shared__ float t[32][33];
  const int c0 = blockIdx.x * 32, r0 = blockIdx.y * 32;
  const int tx = threadIdx.x & 31, ty = threadIdx.x >> 5;   // 32 x 8
#pragma unroll
  for (int i = 0; i < 4; ++i)
    t[ty + i * 8][tx] = src[(size_t)(r0 + ty + i * 8) * C + c0 + tx];
  __syncthreads();
#pragma unroll
  for (int i = 0; i < 4; ++i)
    dst[(size_t)(c0 + ty + i * 8) * ldd + coff + r0 + tx] = t[tx][ty + i * 8];
}

// ---------------------------------------------------------------------------
// fp32 GEMM v7, chain-exact (k-ascending fmaf per output). BK=32.
// A source WT (K, Mtot) k-major -> both A and B staged via global_load_lds
// (float path). u8 path: A via glds, B via register byte-expansion.
// LDS stride 128 (16B-aligned ds_read_b128; reads are <=2-way banked = free).
// Fragment split at t*4 / 64+t*4 (round-6-proven). Fused f64 BN partials.
// ---------------------------------------------------------------------------
template <typename TIN>
__global__ __launch_bounds__(256, 4) void k_gemm7(
    const float* __restrict__ WT, const TIN* __restrict__ X,
    const float* __restrict__ bias, float* __restrict__ Y,
    double* __restrict__ pS, double* __restrict__ pS2, int K, int Mtot) {
  __shared__ float As[32][128];
  __shared__ float Bs[32][128];
  const int tid = threadIdx.x;
  const int lane = tid & 63, wv = tid >> 6;
  const int bn = blockIdx.x, gy = blockIdx.y;
  const int wcol = gy * 128;
  const int tx = tid & 15, ty = tid >> 4;
  const int NK = K >> 5;
  const int lrow = wv * 2 + (lane >> 5);     // wave-relative staging row
  const int lcol = (lane & 31) * 4;          // staging col (floats)

  float acc[8][8];
#pragma unroll
  for (int i = 0; i < 8; ++i)
#pragma unroll
    for (int j = 0; j < 8; ++j) acc[i][j] = 0.f;

  for (int ks = 0; ks < NK; ++ks) {
    const int k0 = ks << 5;
    __syncthreads();   // previous compute done; LDS free
    // ---- stage A (32 x 128) via global_load_lds ----
#pragma unroll
    for (int i = 0; i < 4; ++i)
      GLDS16(WT + (size_t)(k0 + i * 8 + lrow) * Mtot + wcol + lcol,
             &As[i * 8 + wv * 2][0]);
    // ---- stage B ----
    if constexpr (__is_same(TIN, float)) {
#pragma unroll
      for (int i = 0; i < 4; ++i)
        GLDS16(X + (size_t)(k0 + i * 8 + lrow) * NBN + bn * 128 + lcol,
               &Bs[i * 8 + wv * 2][0]);
    } else {
      const int r = tid >> 3, c16 = tid & 7;
      const uint4 d = *reinterpret_cast<const uint4*>(
          &X[(size_t)(k0 + r) * NBN + bn * 128 + c16 * 16]);
      const uint32_t wd[4] = {d.x, d.y, d.z, d.w};
#pragma unroll
      for (int q = 0; q < 4; ++q) {
        float4 f;
        f.x = (float)(wd[q] & 0xffu);
        f.y = (float)((wd[q] >> 8) & 0xffu);
        f.z = (float)((wd[q] >> 16) & 0xffu);
        f.w = (float)(wd[q] >> 24);
        *reinterpret_cast<float4*>(&Bs[r][c16 * 16 + q * 4]) = f;
      }
    }
    asm volatile("s_waitcnt vmcnt(0)" ::: "memory");
    __syncthreads();   // staging visible to all waves
    // ---- compute: k-ascending fused-FMA chain per output ----
#pragma unroll
    for (int kk = 0; kk < 32; ++kk) {
      float a8[8], b8[8];
      *reinterpret_cast<float4*>(&a8[0]) = *reinterpret_cast<const float4*>(&As[kk][ty * 4]);
      *reinterpret_cast<float4*>(&a8[4]) = *reinterpret_cast<const float4*>(&As[kk][64 + ty * 4]);
      *reinterpret_cast<float4*>(&b8[0]) = *reinterpret_cast<const float4*>(&Bs[kk][tx * 4]);
      *reinterpret_cast<float4*>(&b8[4]) = *reinterpret_cast<const float4*>(&Bs[kk][64 + tx * 4]);
#pragma unroll
      for (int i = 0; i < 8; ++i)
#pragma unroll
        for (int j = 0; j < 8; ++j) acc[i][j] = fmaf(a8[i], b8[j], acc[i][j]);
    }
  }

  // ---- epilogue: bias, store, f64 BN partials (identical to round 6) ----
#pragma unroll
  for (int i = 0; i < 8; ++i) {
    const int rl = (i < 4) ? (ty * 4 + i) : (64 + ty * 4 + i - 4);
    const int row = wcol + rl;
    const float bv = bias ? bias[row] : 0.f;
    float4 o0, o1;
    o0.x = acc[i][0] + bv; o0.y = acc[i][1] + bv;
    o0.z = acc[i][2] + bv; o0.w = acc[i][3] + bv;
    o1.x = acc[i][4] + bv; o1.y = acc[i][5] + bv;
    o1.z = acc[i][6] + bv; o1.w = acc[i][7] + bv;
    *reinterpret_cast<float4*>(&Y[(size_t)row * NBN + bn * 128 + tx * 4]) = o0;
    *reinterpret_cast<float4*>(&Y[(size_t)row * NBN + bn * 128 + 64 + tx * 4]) = o1;
    double s = (double)o0.x + (double)o0.y + (double)o0.z + (double)o0.w +
               (double)o1.x + (double)o1.y + (double)o1.z + (double)o1.w;
    double s2 = (double)o0.x * o0.x + (double)o0.y * o0.y + (double)o0.z * o0.z +
                (double)o0.w * o0.w + (double)o1.x * o1.x + (double)o1.y * o1.y +
                (double)o1.z * o1.z + (double)o1.w * o1.w;
#pragma unroll
    for (int off = 1; off < 16; off <<= 1) {
      s += __shfl_xor(s, off, 64);
      s2 += __shfl_xor(s2, off, 64);
    }
    if (tx == 0) {
      pS[(size_t)bn * Mtot + row] = s;
      pS2[(size_t)bn * Mtot + row] = s2;
    }
  }
}

// ---- BN stat reduce: 196 f64 partials per channel --------------------------
__global__ __launch_bounds__(64) void k_bn_reduce3(const double* __restrict__ pS,
                                                   const double* __restrict__ pS2,
                                                   float* __restrict__ mean,
                                                   float* __restrict__ rstd, int Mtot) {
  const int ch = blockIdx.x, lane = threadIdx.x;
  double s = 0.0, s2 = 0.0;
  for (int j = lane; j < 196; j += 64) {
    s += pS[(size_t)j * Mtot + ch];
    s2 += pS2[(size_t)j * Mtot + ch];
  }
#pragma unroll
  for (int off = 32; off; off >>= 1) {
    s += __shfl_down(s, off, 64);
    s2 += __shfl_down(s2, off, 64);
  }
  if (lane == 0) {
    double m = s / (double)NBN;
    double v = s2 / (double)NBN - m * m;
    mean[ch] = (float)m;
    rstd[ch] = (float)(1.0 / sqrt(v + 1e-5));
  }
}

// ---- BN apply + LIF (thr 1.0) writing PACKED spikes (qkv -> attention) -----
__global__ __launch_bounds__(256) void k_lif_pack(const float* __restrict__ Y,
    const float* __restrict__ mean, const float* __restrict__ rstd,
    const float* __restrict__ g0, const float* __restrict__ g1,
    const float* __restrict__ g2, const float* __restrict__ b0,
    const float* __restrict__ b1, const float* __restrict__ b2,
    uint32_t* __restrict__ pk) {
  const int o = blockIdx.x;
  const int b = threadIdx.x >> 3, w = threadIdx.x & 7;
  int br = o / 384, ol = o - br * 384;
  const float g = (br == 0 ? g0 : br == 1 ? g1 : g2)[ol];
  const float be = (br == 0 ? b0 : br == 1 ? b1 : b2)[ol];
  const float m_ = mean[o], rs_ = rstd[o];
  float mem[32];
#pragma unroll
  for (int j = 0; j < 32; ++j) mem[j] = 0.f;
  for (int t = 0; t < 4; ++t) {
    uint32_t word = 0;
    const size_t base = (size_t)o * NBN + (size_t)(t * 32 + b) * NTOK + w * 32;
#pragma unroll
    for (int q = 0; q < 8; ++q) {
      if (w * 32 + q * 4 < NTOK) {
        float4 v4 = *reinterpret_cast<const float4*>(&Y[base + q * 4]);
        float vv[4] = {v4.x, v4.y, v4.z, v4.w};
#pragma unroll
        for (int jj = 0; jj < 4; ++jj) {
          int j = q * 4 + jj;
          float v = ((vv[jj] - m_) * rs_) * g + be;
          float mm = mem[j];
          mm = mm + (v - mm) * 0.5f;
          bool fire = (mm >= 1.0f);
          mem[j] = fire ? 0.f : mm;
          word |= (fire ? 1u : 0u) << j;
        }
      }
    }
    pk[((size_t)o * 128 + t * 32 + b) * 8 + w] = word;
  }
}

// ---- BN apply + LIF (thr 1.0) writing u8 spikes (fc1 -> fc2 B) -------------
__global__ __launch_bounds__(256) void k_lif_u8(const float* __restrict__ Y,
    const float* __restrict__ mean, const float* __restrict__ rstd,
    const float* __restrict__ gamma, const float* __restrict__ beta,
    uint8_t* __restrict__ sp) {
  const int o = blockIdx.x;
  const int b = threadIdx.x >> 3, w = threadIdx.x & 7;
  const float m_ = mean[o], rs_ = rstd[o], g = gamma[o], be = beta[o];
  float mem[32];
#pragma unroll
  for (int j = 0; j < 32; ++j) mem[j] = 0.f;
  for (int t = 0; t < 4; ++t) {
    const size_t base = (size_t)o * NBN + (size_t)(t * 32 + b) * NTOK + w * 32;
    uint32_t words[8];
#pragma unroll
    for (int q = 0; q < 8; ++q) {
      words[q] = 0;
      if (w * 32 + q * 4 < NTOK) {
        float4 v4 = *reinterpret_cast<const float4*>(&Y[base + q * 4]);
        float vv[4] = {v4.x, v4.y, v4.z, v4.w};
#pragma unroll
        for (int jj = 0; jj < 4; ++jj) {
          int j = q * 4 + jj;
          float v = ((vv[jj] - m_) * rs_) * g + be;
          float mm = mem[j];
          mm = mm + (v - mm) * 0.5f;
          bool fire = (mm >= 1.0f);
          mem[j] = fire ? 0.f : mm;
          words[q] |= (fire ? 1u : 0u) << (8 * jj);
        }
      }
    }
    uint32_t* dst = reinterpret_cast<uint32_t*>(const_cast<uint8_t*>(sp) + base);
#pragma unroll
    for (int q = 0; q < 8; ++q)
      if (w * 32 + q * 4 < NTOK) dst[q] = words[q];
  }
}

// ---- BN apply + LIF, float outputs -----------------------------------------
template <int MODE>
__global__ __launch_bounds__(256) void k_bn_lif(const float* __restrict__ Y,
                                                const float* __restrict__ mean,
                                                const float* __restrict__ rstd,
                                                const float* __restrict__ gamma,
                                                const float* __restrict__ beta,
                                                const float* __restrict__ addsrc,
                                                float* __restrict__ extra) {
  int id = blockIdx.x * 256 + threadIdx.x;
  int o = id / (BATCH * NTOK);
  int r = id - o * (BATCH * NTOK);
  float m_ = mean[o], rs_ = rstd[o], g = gamma[o], be = beta[o];
  float mem = 0.f;
#pragma unroll
  for (int t = 0; t < 4; ++t) {
    size_t idx = (size_t)o * NBN + (size_t)t * (BATCH * NTOK) + r;
    float v = Y[idx];
    v = ((v - m_) * rs_) * g + be;
    mem = mem + (v - mem) * 0.5f;
    bool fire = (mem >= 1.0f);
    float s = fire ? 1.f : 0.f;
    mem = fire ? 0.f : mem;
    if constexpr (MODE == 1) {
      extra[idx] = addsrc[idx] + s;
    } else {
      int b = r / NTOK, n = r - b * NTOK;
      extra[((size_t)(t * BATCH + b) * CDIM + o) * NTOK + n] = addsrc[idx] + s;
    }
  }
}

// ---- attention via popcount (exact integers), u8 output --------------------
__global__ __launch_bounds__(256) void k_attn_pop(const uint32_t* __restrict__ pQ,
                                                  const uint32_t* __restrict__ pK,
                                                  const uint32_t* __restrict__ pV,
                                                  uint8_t* __restrict__ spA) {
  __shared__ __align__(16) uint32_t qw[32][8], kw[32][8], vw[32][8];
  __shared__ int kv[32][33];
  __shared__ uint32_t kvb[8][32];
  __shared__ uint32_t qT[NTOK];
  const int bh = blockIdx.x;
  const int b_ = bh / NHEAD, h = bh - b_ * NHEAD;
  const int tid = threadIdx.x;
  const int e = tid >> 3, w = tid & 7;
  float mem[32];
#pragma unroll
  for (int j = 0; j < 32; ++j) mem[j] = 0.f;

  for (int t = 0; t < 4; ++t) {
    const int tb = t * 32 + b_;
    {
      int d = tid >> 3, wo = tid & 7;
      size_t base = ((size_t)(h * 32 + d) * 128 + tb) * 8 + wo;
      qw[d][wo] = pQ[base];
      kw[d][wo] = pK[base];
      vw[d][wo] = pV[base];
    }
    __syncthreads();
    for (int i = tid; i < 1024; i += 256) {
      int d = i >> 5, ee = i & 31;
      const uint64_t* kp = reinterpret_cast<const uint64_t*>(&kw[d][0]);
      const uint64_t* vp = reinterpret_cast<const uint64_t*>(&vw[ee][0]);
      int s = 0;
#pragma unroll
      for (int u = 0; u < 4; ++u) s += __popcll(kp[u] & vp[u]);
      kv[d][ee] = s;
    }
    __syncthreads();
    {
      int bitb = tid >> 5, ee = tid & 31;
      uint32_t mword = 0;
#pragma unroll
      for (int d = 0; d < 32; ++d) mword |= (uint32_t)((kv[d][ee] >> bitb) & 1) << d;
      kvb[bitb][ee] = mword;
    }
    if (tid < NTOK) {
      uint32_t mword = 0;
#pragma unroll
      for (int d = 0; d < 32; ++d)
        mword |= ((qw[d][tid >> 5] >> (tid & 31)) & 1u) << d;
      qT[tid] = mword;
    }
    __syncthreads();
    uint32_t word = 0;
#pragma unroll
    for (int j = 0; j < 32; ++j) {
      int n = w * 32 + j;
      if (n < NTOK) {
        uint32_t qm = qT[n];
        int acc = 0;
#pragma unroll
        for (int bb = 0; bb < 8; ++bb) acc += __popc(qm & kvb[bb][e]) << bb;
        float val = (float)acc * 0.125f;
        float mm = mem[j];
        mm = mm + (val - mm) * 0.5f;
        bool fire = (mm >= 0.5f);
        mem[j] = fire ? 0.f : mm;
        word |= (fire ? 1u : 0u) << j;
      }
    }
    uint8_t* dst = spA + (size_t)(h * 32 + e) * NBN + (size_t)tb * NTOK + w * 32;
#pragma unroll
    for (int q = 0; q < 8; ++q) {
      if (w * 32 + q * 4 < NTOK) {
        uint32_t b4 = ((word >> (q * 4)) & 1u) | (((word >> (q * 4 + 1)) & 1u) << 8) |
                      (((word >> (q * 4 + 2)) & 1u) << 16) |
                      (((word >> (q * 4 + 3)) & 1u) << 24);
        *reinterpret_cast<uint32_t*>(dst + q * 4) = b4;
      }
    }
    __syncthreads();
  }
}

// ---------------------------------------------------------------------------
extern "C" void kernel_launch(void* const* d_in, const int* in_sizes, int n_in,
                              void* d_out, int out_size, void* d_ws, size_t ws_size,
                              hipStream_t stream) {
  const float* x          = (const float*)d_in[0];
  const float* q_w        = (const float*)d_in[1];
  const float* q_gamma    = (const float*)d_in[2];
  const float* q_beta     = (const float*)d_in[3];
  const float* k_w        = (const float*)d_in[4];
  const float* k_gamma    = (const float*)d_in[5];
  const float* k_beta     = (const float*)d_in[6];
  const float* v_w        = (const float*)d_in[7];
  const float* v_gamma    = (const float*)d_in[8];
  const float* v_beta     = (const float*)d_in[9];
  const float* proj_w     = (const float*)d_in[10];
  const float* proj_b     = (const float*)d_in[11];
  const float* proj_gamma = (const float*)d_in[12];
  const float* proj_beta  = (const float*)d_in[13];
  const float* fc1_w      = (const float*)d_in[14];
  const float* fc1_b      = (const float*)d_in[15];
  const float* bn1_gamma  = (const float*)d_in[16];
  const float* bn1_beta   = (const float*)d_in[17];
  const float* fc2_w      = (const float*)d_in[18];
  const float* fc2_b      = (const float*)d_in[19];
  const float* bn2_gamma  = (const float*)d_in[20];
  const float* bn2_beta   = (const float*)d_in[21];
  float* out = (float*)d_out;
  char* ws = (char*)d_ws;

  // ---- arena (bytes); peak 231,223,296 = round-1-proven footprint --------
  // persistent-phase buffers:
  const size_t O_XT   = 0;           // xT f32 (384,NBN) 38,535,168 [live: 1..proj-lif]
  const size_t O_YQ   = 38535168;    // yQKV (1152,NBN) / yB / fc2 yB
  const size_t O_XRES = 154140672;   // xres (384,NBN) [live: proj-lif..end]
  const size_t O_PK   = 192675840;   // packed qkv bits 4,718,592 [qkv-lif..attn]
  const size_t O_SPA  = 197394432;   // attn u8 spikes 9,633,792 [attn..proj gemm]
  const size_t O_H1SP = 192675840;   // u8 (1536,NBN) 38,535,168 [fc1-lif..fc2 gemm]
  const size_t O_H1   = 0;           // fc1 out f32 (1536,NBN) 154,140,672
  const size_t O_ST   = 231211008;   // mean/rstd (<=1536 ch each)
  // transient (lifetime-verified, stream-ordered):
  const size_t O_P1   = 154140672;   // qkv/proj partials (consumed pre-xres)
  const size_t O_P1B  = O_P1 + 1806336;
  const size_t O_QKVT = 197394432;   // qkvT 1,769,472 [pre-attn]
  const size_t O_PRJT = 192675840;   // projT 589,824 [post-attn, pre-h1sp]
  const size_t O_P2A  = 192675840;   // fc1 partials 2x2,408,448 [pre-h1sp]
  const size_t O_P2AB = O_P2A + 2408448;
  const size_t O_F1T  = 197492736;   // fc1T 2,359,296 [pre-h1sp]
  const size_t O_P2B  = 0;           // fc2 partials 2x602,112 [h1 dead]
  const size_t O_P2BB = 602112;
  const size_t O_F2T  = 1204224;     // fc2T 2,359,296 [h1 dead]

  float* xT    = (float*)(ws + O_XT);
  float* yQ    = (float*)(ws + O_YQ);
  float* yB    = (float*)(ws + O_YQ);
  float* h1    = (float*)(ws + O_H1);
  float* xres  = (float*)(ws + O_XRES);
  uint32_t* pkQKV = (uint32_t*)(ws + O_PK);
  uint8_t* spA   = (uint8_t*)(ws + O_SPA);
  uint8_t* h1sp  = (uint8_t*)(ws + O_H1SP);
  float* qkvT  = (float*)(ws + O_QKVT);
  float* projT = (float*)(ws + O_PRJT);
  float* fc1T  = (float*)(ws + O_F1T);
  float* fc2T  = (float*)(ws + O_F2T);
  double* p1S  = (double*)(ws + O_P1);
  double* p1S2 = (double*)(ws + O_P1B);
  double* p2aS  = (double*)(ws + O_P2A);
  double* p2aS2 = (double*)(ws + O_P2AB);
  double* p2bS  = (double*)(ws + O_P2B);
  double* p2bS2 = (double*)(ws + O_P2BB);
  float* mean_ = (float*)(ws + O_ST);
  float* rstd_ = (float*)(ws + O_ST + 6144);

  // 1. input transpose + qkv weight transpose (k-major, concatenated)
  k_transpose<<<dim3(CDIM * NBN / 256), 256, 0, stream>>>(x, xT);
  k_wT<<<dim3(12, 12), 256, 0, stream>>>(q_w, qkvT, 384, 1152, 0);
  k_wT<<<dim3(12, 12), 256, 0, stream>>>(k_w, qkvT, 384, 1152, 384);
  k_wT<<<dim3(12, 12), 256, 0, stream>>>(v_w, qkvT, 384, 1152, 768);

  // 2. fused q/k/v GEMM (chain-exact, glds-staged) + BN partials + packed LIF
  k_gemm7<float><<<dim3(196, 9), 256, 0, stream>>>(
      qkvT, xT, (const float*)nullptr, yQ, p1S, p1S2, CDIM, 1152);
  k_bn_reduce3<<<dim3(1152), 64, 0, stream>>>(p1S, p1S2, mean_, rstd_, 1152);
  k_lif_pack<<<dim3(1152), 256, 0, stream>>>(
      yQ, mean_, rstd_, q_gamma, k_gamma, v_gamma, q_beta, k_beta, v_beta, pkQKV);

  // 3. attention (exact integer popcount) -> u8 spikes
  k_attn_pop<<<dim3(BATCH * NHEAD), 256, 0, stream>>>(
      pkQKV, pkQKV + 393216, pkQKV + 786432, spA);

  // 4. proj GEMM (u8 B) + BN + residual -> xres
  k_wT<<<dim3(12, 12), 256, 0, stream>>>(proj_w, projT, 384, 384, 0);
  k_gemm7<uint8_t><<<dim3(196, 3), 256, 0, stream>>>(
      projT, spA, proj_b, yB, p1S, p1S2, CDIM, 384);
  k_bn_reduce3<<<dim3(384), 64, 0, stream>>>(p1S, p1S2, mean_, rstd_, 384);
  k_bn_lif<1><<<dim3(9408), 256, 0, stream>>>(yB, mean_, rstd_, proj_gamma, proj_beta,
                                              xT, xres);

  // 5. fc1 GEMM (float B = xres), single dispatch M=1536 -> u8 spikes
  k_wT<<<dim3(12, 48), 256, 0, stream>>>(fc1_w, fc1T, 384, 1536, 0);
  k_gemm7<float><<<dim3(196, 12), 256, 0, stream>>>(
      fc1T, xres, fc1_b, h1, p2aS, p2aS2, CDIM, 1536);
  k_bn_reduce3<<<dim3(1536), 64, 0, stream>>>(p2aS, p2aS2, mean_, rstd_, 1536);
  k_lif_u8<<<dim3(1536), 256, 0, stream>>>(h1, mean_, rstd_,
                                           bn1_gamma, bn1_beta, h1sp);

  // 6. fc2 GEMM (u8 B, K=1536) + final BN + residual -> out
  k_wT<<<dim3(48, 12), 256, 0, stream>>>(fc2_w, fc2T, 1536, 384, 0);
  k_gemm7<uint8_t><<<dim3(196, 3), 256, 0, stream>>>(
      fc2T, h1sp, fc2_b, yB, p2bS, p2bS2, HDIM, 384);
  k_bn_reduce3<<<dim3(384), 64, 0, stream>>>(p2bS, p2bS2, mean_, rstd_, 384);
  k_bn_lif<2><<<dim3(9408), 256, 0, stream>>>(yB, mean_, rstd_, bn2_gamma, bn2_beta,
                                              xres, out);
}